// Round 9
// baseline (49.676 us; speedup 1.0000x reference)
//
#include <hip/hip_runtime.h>
#include <hip/hip_bf16.h>

// Encoder: B=16, n=1024, C=256, K=32, fp32 in/out.
// 2-kernel pipeline:
//  1) enc_main (256 blocks x 512 thr): GEMM1 dot=x.cw^T (MFMA) -> softmax ->
//     GEMM2 S1=w^T.x (MFMA, accumulators persist across 2 position-tiles)
//     -> per-block partials pS1/pW. Also zeroes the tail's arrival counters.
//  2) enc_tail (512 blocks x 256 thr, all co-resident): 3 phases chained by
//     device-scope arrival counters (release add / acquire spin):
//       P1 (512 blocks): sum 16 partials -> enc row
//       P2 (blocks 0-63): per-channel stat partials over 8 rows
//       P3 (blocks 0-15): BN finalize + ReLU + sum_k -> out
//     NOTE: cg::this_grid().sync() measured ~70us/sync on MI355X (R7) --
//     hand-rolled counters are ~1us. Static phase assignment => deterministic.

#define BN_EPS 1e-3f

typedef __attribute__((ext_vector_type(8))) short short8;
typedef __attribute__((ext_vector_type(4))) float f32x4;

static __device__ inline unsigned short f2bf(float f) {
    unsigned int u = __float_as_uint(f);
    unsigned int r = (u + 0x7fffu + ((u >> 16) & 1u)) >> 16;
    return (unsigned short)r;
}

static __device__ inline short8 pack8(float4 u, float4 v) {
    short8 r;
    r[0] = (short)f2bf(u.x); r[1] = (short)f2bf(u.y);
    r[2] = (short)f2bf(u.z); r[3] = (short)f2bf(u.w);
    r[4] = (short)f2bf(v.x); r[5] = (short)f2bf(v.y);
    r[6] = (short)f2bf(v.z); r[7] = (short)f2bf(v.w);
    return r;
}

#if __has_builtin(__builtin_amdgcn_global_load_lds)
#define HAVE_GLOAD_LDS 1
typedef const __attribute__((address_space(1))) void* as1_cvp;
typedef __attribute__((address_space(3))) void* as3_vp;
static __device__ inline void gload_lds16(const void* g, void* s) {
    __builtin_amdgcn_global_load_lds((as1_cvp)g, (as3_vp)s, 16, 0, 0);
}
#else
#define HAVE_GLOAD_LDS 0
#endif

// ------------- MFMA main kernel: 256 blocks x 512 thr, 2 tiles/block ---------
__global__ __launch_bounds__(512, 1) void enc_main_mfma(
    const float* __restrict__ x, const float* __restrict__ cw,
    const float* __restrict__ sf, float* __restrict__ pS1, float* __restrict__ pW,
    unsigned int* __restrict__ ctrs)
{
    const int bid = blockIdx.x;          // 256 blocks
    const int b   = bid >> 4;            // batch
    const int jb2 = bid & 15;            // 64-position super-tile
    const int t = threadIdx.x;
    const int w = t >> 6;                // 8 waves
    const int lane = t & 63;
    const int mt   = w >> 2;             // M-tile (16 rows)
    const int half = (w >> 1) & 1;       // channel half (128)
    const int dup  = w & 1;              // ks-half (2 of 4 k-slices)
    const int lrow = lane & 15;
    const int g    = lane >> 4;

    if (bid == 0 && t < 2) ctrs[t] = 0;  // tail arrival counters (kernel-boundary ordered)

    __shared__ float4 xs4[32][65];             // x tile fp32 (reused tile1)
    __shared__ unsigned short cwbf[32][264];   // cw bf16 (block-lifetime)
    __shared__ float  ccred[16][32];
    __shared__ float4 dred[2][2][2][2][64];    // [mt][half][dup][nt][lane]
    __shared__ float  xxr[2][2][2][16];        // [mt][half][dup][pos]
    __shared__ unsigned short xbf[32][264];    // x bf16 (per tile)
    __shared__ unsigned short wT[32][40];      // w^T bf16 (per tile)
    __shared__ float  w_lds[2][32][33];        // fp32 w per tile (wsum)
    __shared__ float  cc_lds[32];
    __shared__ float  sf_lds[32];

    const float4* gx4 = (const float4*)(x + (size_t)b * 1024 * 256)
                        + (size_t)jb2 * 64 * 64;

    // ---- phase 0: DMA tile0 -> xs4; pack cw->bf16 + cc partials; sf ----
#if HAVE_GLOAD_LDS
    #pragma unroll
    for (int i = 0; i < 4; ++i) {
        const int row = w * 4 + i;
        gload_lds16(gx4 + row * 64 + lane, &xs4[row][0]);
    }
#else
    {
        const int p = t >> 4, q = t & 15;
        #pragma unroll
        for (int j = 0; j < 4; ++j)
            xs4[p][q + 16 * j] = gx4[p * 64 + q + 16 * j];
    }
#endif
    {
        const int k = t >> 4, seg = t & 15;  // 16 channels per thread
        const float4* cw4 = (const float4*)cw;
        float s = 0.f;
        #pragma unroll
        for (int jj = 0; jj < 2; ++jj) {
            float4 u0 = cw4[k * 64 + seg * 4 + 2 * jj];
            float4 u1 = cw4[k * 64 + seg * 4 + 2 * jj + 1];
            s += u0.x * u0.x + u0.y * u0.y + u0.z * u0.z + u0.w * u0.w
               + u1.x * u1.x + u1.y * u1.y + u1.z * u1.z + u1.w * u1.w;
            *(short8*)&cwbf[k][seg * 16 + 8 * jj] = pack8(u0, u1);
        }
        ccred[seg][k] = s;
    }
    if (t < 32) sf_lds[t] = sf[t];
    __syncthreads();

    if (t < 32) {                        // overlaps GEMM1; read post-bar1
        float s = 0.f;
        #pragma unroll
        for (int j = 0; j < 16; ++j) s += ccred[j][t];
        cc_lds[t] = s;
    }

    f32x4 E00 = {0,0,0,0}, E01 = {0,0,0,0}, E10 = {0,0,0,0}, E11 = {0,0,0,0};
    const float* xsf = (const float*)xs4;

    #pragma unroll
    for (int tile = 0; tile < 2; ++tile) {
        // ---- GEMM1: dot = x.cw^T (this wave: 2 of 4 k-slices); write xbf ----
        f32x4 D0 = {0,0,0,0}, D1 = {0,0,0,0};
        float xxp = 0.f;
        #pragma unroll
        for (int k2 = 0; k2 < 2; ++k2) {
            const int ks = dup * 2 + k2;
            const int ch = half * 128 + ks * 32 + g * 8;
            const int row = mt * 16 + lrow;
            const float* ap = xsf + row * 260 + ch;
            float4 uu = *(const float4*)ap;
            float4 vv = *(const float4*)(ap + 4);
            xxp += uu.x * uu.x + uu.y * uu.y + uu.z * uu.z + uu.w * uu.w
                 + vv.x * vv.x + vv.y * vv.y + vv.z * vv.z + vv.w * vv.w;
            short8 a = pack8(uu, vv);
            *(short8*)&xbf[row][ch] = a;
            short8 b0 = *(const short8*)&cwbf[lrow][ch];
            short8 b1 = *(const short8*)&cwbf[16 + lrow][ch];
            D0 = __builtin_amdgcn_mfma_f32_16x16x32_bf16(a, b0, D0, 0, 0, 0);
            D1 = __builtin_amdgcn_mfma_f32_16x16x32_bf16(a, b1, D1, 0, 0, 0);
        }
        xxp += __shfl_xor(xxp, 16, 64);
        xxp += __shfl_xor(xxp, 32, 64);
        if (lane < 16) xxr[mt][half][dup][lane] = xxp;
        dred[mt][half][dup][0][lane] = make_float4(D0[0], D0[1], D0[2], D0[3]);
        dred[mt][half][dup][1][lane] = make_float4(D1[0], D1[1], D1[2], D1[3]);
        __syncthreads();                               // bar1

        if (tile == 0) {
            // prefetch tile1 into xs4; stays in flight across raw bar2
#if HAVE_GLOAD_LDS
            #pragma unroll
            for (int i = 0; i < 4; ++i) {
                const int row = w * 4 + i;
                gload_lds16(gx4 + (32 + row) * 64 + lane, &xs4[row][0]);
            }
#else
            const int p = t >> 4, q = t & 15;
            #pragma unroll
            for (int j = 0; j < 4; ++j)
                xs4[p][q + 16 * j] = gx4[(32 + p) * 64 + q + 16 * j];
#endif
        }

        // ---- softmax over k (all waves compute; (half,dup)==(0,0) writes) ---
        {
            const int k0 = lrow, k1 = 16 + lrow;
            float d0[4], d1[4];
            #pragma unroll
            for (int nt = 0; nt < 2; ++nt) {
                float4 s00 = dred[mt][0][0][nt][lane];
                float4 s01 = dred[mt][0][1][nt][lane];
                float4 s10 = dred[mt][1][0][nt][lane];
                float4 s11 = dred[mt][1][1][nt][lane];
                float* dd = nt ? d1 : d0;
                dd[0] = s00.x + s01.x + s10.x + s11.x;
                dd[1] = s00.y + s01.y + s10.y + s11.y;
                dd[2] = s00.z + s01.z + s10.z + s11.z;
                dd[3] = s00.w + s01.w + s10.w + s11.w;
            }
            const float sf0 = sf_lds[k0], sf1 = sf_lds[k1];
            const float cc0 = cc_lds[k0], cc1 = cc_lds[k1];
            #pragma unroll
            for (int r = 0; r < 4; ++r) {
                const int pl = g * 4 + r;
                const float xxv = xxr[mt][0][0][pl] + xxr[mt][0][1][pl]
                                + xxr[mt][1][0][pl] + xxr[mt][1][1][pl];
                float s0 = sf0 * (xxv - 2.f * d0[r] + cc0);
                float s1 = sf1 * (xxv - 2.f * d1[r] + cc1);
                float m = fmaxf(s0, s1);
                #pragma unroll
                for (int msk = 1; msk <= 8; msk <<= 1) m = fmaxf(m, __shfl_xor(m, msk, 64));
                float e0 = __expf(s0 - m), e1 = __expf(s1 - m);
                float sm = e0 + e1;
                #pragma unroll
                for (int msk = 1; msk <= 8; msk <<= 1) sm += __shfl_xor(sm, msk, 64);
                const float inv = 1.f / sm;
                if (half == 0 && dup == 0) {
                    const int n = mt * 16 + pl;
                    const float w0v = e0 * inv, w1v = e1 * inv;
                    w_lds[tile][n][k0] = w0v;
                    w_lds[tile][n][k1] = w1v;
                    wT[k0][n] = f2bf(w0v);
                    wT[k1][n] = f2bf(w1v);
                }
            }
        }
        // bar2: execution + LDS drain only; DMA (vmcnt) stays in flight
        asm volatile("s_waitcnt lgkmcnt(0)" ::: "memory");
        __builtin_amdgcn_sched_barrier(0);
        __builtin_amdgcn_s_barrier();
        __builtin_amdgcn_sched_barrier(0);

        // ---- GEMM2: accumulate S1 fragments across tiles ----
        {
            short8 a0 = *(const short8*)&wT[lrow][8 * g];
            short8 a1 = *(const short8*)&wT[16 + lrow][8 * g];
            const unsigned short* xbu = &xbf[0][0];
            #pragma unroll
            for (int nt = 0; nt < 2; ++nt) {
                const int c = w * 32 + nt * 16 + lrow;
                short8 bf;
                #pragma unroll
                for (int e = 0; e < 8; ++e)
                    bf[e] = (short)xbu[(8 * g + e) * 264 + c];
                if (nt == 0) {
                    E00 = __builtin_amdgcn_mfma_f32_16x16x32_bf16(a0, bf, E00, 0, 0, 0);
                    E10 = __builtin_amdgcn_mfma_f32_16x16x32_bf16(a1, bf, E10, 0, 0, 0);
                } else {
                    E01 = __builtin_amdgcn_mfma_f32_16x16x32_bf16(a0, bf, E01, 0, 0, 0);
                    E11 = __builtin_amdgcn_mfma_f32_16x16x32_bf16(a1, bf, E11, 0, 0, 0);
                }
            }
        }
        if (tile == 0) __syncthreads();    // bar3: drains DMA; xbf/wT reusable
    }

    // ---- stores: one 32x256 partial per block ----
    float* dst = pS1 + (size_t)bid * 8192;
    #pragma unroll
    for (int reg = 0; reg < 4; ++reg) {
        const int k0r = (4 * g + reg) * 256;
        const int k1r = (16 + 4 * g + reg) * 256;
        dst[k0r + w * 32 +  0 + lrow] = E00[reg];
        dst[k0r + w * 32 + 16 + lrow] = E01[reg];
        dst[k1r + w * 32 +  0 + lrow] = E10[reg];
        dst[k1r + w * 32 + 16 + lrow] = E11[reg];
    }
    if (t < 32) {
        float s = 0.f;
        #pragma unroll
        for (int p = 0; p < 32; ++p) s += w_lds[0][p][t] + w_lds[1][p][t];
        pW[bid * 32 + t] = s;
    }
}

// -------- fused tail: reduce -> stats -> out, chained by arrival counters ----
// 512 blocks x 256 thr, LDS-free, 4 waves/block -> all blocks co-resident
// (2048 waves << 8192 capacity), so fixed blockIdx phase assignment is safe.
__global__ __launch_bounds__(256) void enc_tail(
    const float* __restrict__ pS1, const float* __restrict__ pW,
    const float* __restrict__ cw, const float* __restrict__ gamma,
    const float* __restrict__ beta, float* __restrict__ enc,
    float* __restrict__ pst, unsigned int* __restrict__ ctrs,
    float* __restrict__ out)
{
    const int bid = blockIdx.x;        // 512
    const int c = threadIdx.x;         // 256

    // ---- phase 1: one (b,k) enc row from 16 partials ----
    {
        const int b = bid >> 5, k = bid & 31;
        float s = 0.f;
        #pragma unroll
        for (int jj = 0; jj < 16; ++jj)
            s += pS1[(size_t)(b * 16 + jj) * 8192 + k * 256 + c];
        float wp = pW[(b * 16 + (c & 15)) * 32 + k];
        #pragma unroll
        for (int m = 1; m <= 8; m <<= 1) wp += __shfl_xor(wp, m, 64);
        enc[bid * 256 + c] = s - wp * cw[k * 256 + c];
    }
    __syncthreads();
    if (c == 0) {
        __threadfence();
        __hip_atomic_fetch_add(&ctrs[0], 1u, __ATOMIC_RELEASE, __HIP_MEMORY_SCOPE_AGENT);
    }
    if (bid >= 64) return;

    // ---- phase 2: stat partials over 8 rows (blocks 0-63) ----
    if (c == 0) {
        while (__hip_atomic_load(&ctrs[0], __ATOMIC_ACQUIRE, __HIP_MEMORY_SCOPE_AGENT) < 512u)
            __builtin_amdgcn_s_sleep(8);
    }
    __syncthreads();
    {
        float s = 0.f, ss = 0.f;
        #pragma unroll
        for (int r = 0; r < 8; ++r) {
            float v = enc[(bid * 8 + r) * 256 + c];
            s += v;
            ss = fmaf(v, v, ss);
        }
        pst[bid * 512 + c] = s;
        pst[bid * 512 + 256 + c] = ss;
    }
    __syncthreads();
    if (c == 0) {
        __threadfence();
        __hip_atomic_fetch_add(&ctrs[1], 1u, __ATOMIC_RELEASE, __HIP_MEMORY_SCOPE_AGENT);
    }
    if (bid >= 16) return;

    // ---- phase 3: BN finalize + ReLU + sum_k -> out (blocks 0-15) ----
    if (c == 0) {
        while (__hip_atomic_load(&ctrs[1], __ATOMIC_ACQUIRE, __HIP_MEMORY_SCOPE_AGENT) < 64u)
            __builtin_amdgcn_s_sleep(8);
    }
    __syncthreads();
    {
        float S = 0.f, SS = 0.f;
        #pragma unroll 8
        for (int p = 0; p < 64; ++p) {
            S  += pst[p * 512 + c];
            SS += pst[p * 512 + 256 + c];
        }
        const float mean = S * (1.f / 512.f);
        const float var = SS * (1.f / 512.f) - mean * mean;
        const float g = gamma[c] * rsqrtf(var + BN_EPS);
        const float bt = beta[c];
        float o = 0.f;
        #pragma unroll
        for (int k = 0; k < 32; ++k) {
            float e = enc[(bid * 32 + k) * 256 + c];
            float v = (e - mean) * g + bt;
            o += fmaxf(v, 0.f);
        }
        out[bid * 256 + c] = o;
    }
}

extern "C" void kernel_launch(void* const* d_in, const int* in_sizes, int n_in,
                              void* d_out, int out_size, void* d_ws, size_t ws_size,
                              hipStream_t stream) {
    const float* x     = (const float*)d_in[0];
    const float* cw    = (const float*)d_in[1];
    const float* sf    = (const float*)d_in[2];
    const float* gamma = (const float*)d_in[3];
    const float* beta  = (const float*)d_in[4];
    float* out = (float*)d_out;
    float* ws  = (float*)d_ws;

    float* pS1 = ws;                               // 256*8192
    float* pW  = pS1 + (size_t)256 * 8192;         // 256*32
    float* enc = pW + (size_t)256 * 32;            // 512*256
    float* pst = enc + (size_t)512 * 256;          // 64*512
    unsigned int* ctrs = (unsigned int*)(pst + (size_t)64 * 512);

    enc_main_mfma<<<256, 512, 0, stream>>>(x, cw, sf, pS1, pW, ctrs);
    enc_tail<<<512, 256, 0, stream>>>(pS1, pW, cw, gamma, beta, enc, pst, ctrs, out);
}

// Round 10
// 25.541 us; speedup vs baseline: 1.9450x; 1.9450x over previous
//
#include <hip/hip_runtime.h>
#include <hip/hip_bf16.h>

// Encoder: B=16, n=1024, C=256, K=32, fp32 in/out.
// 3-kernel pipeline (R6 anchor + fused tail):
//  1) enc_main (256 blocks x 512 thr): GEMM1 dot=x.cw^T (MFMA) -> softmax ->
//     GEMM2 S1=w^T.x (MFMA, accumulators persist across 2 position-tiles)
//     -> per-block partials pS1/pW
//  2) enc_reduce_stats (64 blocks x 512 thr): 8 rows/block: sum 16 partials ->
//     enc rows + per-channel stat partials (LDS-combined) -> pst[64][512]
//  3) enc_out (16 blocks): BN finalize + ReLU + sum_k -> out
// Measured-and-banned on MI355X: cg grid-sync ~70us/sync (R7); device-scope
// fence+atomic chaining +23us (R9). Kernel boundaries (~1.5-2us) win.

#define BN_EPS 1e-3f

typedef __attribute__((ext_vector_type(8))) short short8;
typedef __attribute__((ext_vector_type(4))) float f32x4;

static __device__ inline unsigned short f2bf(float f) {
    unsigned int u = __float_as_uint(f);
    unsigned int r = (u + 0x7fffu + ((u >> 16) & 1u)) >> 16;
    return (unsigned short)r;
}

static __device__ inline short8 pack8(float4 u, float4 v) {
    short8 r;
    r[0] = (short)f2bf(u.x); r[1] = (short)f2bf(u.y);
    r[2] = (short)f2bf(u.z); r[3] = (short)f2bf(u.w);
    r[4] = (short)f2bf(v.x); r[5] = (short)f2bf(v.y);
    r[6] = (short)f2bf(v.z); r[7] = (short)f2bf(v.w);
    return r;
}

#if __has_builtin(__builtin_amdgcn_global_load_lds)
#define HAVE_GLOAD_LDS 1
typedef const __attribute__((address_space(1))) void* as1_cvp;
typedef __attribute__((address_space(3))) void* as3_vp;
static __device__ inline void gload_lds16(const void* g, void* s) {
    __builtin_amdgcn_global_load_lds((as1_cvp)g, (as3_vp)s, 16, 0, 0);
}
#else
#define HAVE_GLOAD_LDS 0
#endif

// ------------- MFMA main kernel: 256 blocks x 512 thr, 2 tiles/block ---------
__global__ __launch_bounds__(512, 1) void enc_main_mfma(
    const float* __restrict__ x, const float* __restrict__ cw,
    const float* __restrict__ sf, float* __restrict__ pS1, float* __restrict__ pW)
{
    const int bid = blockIdx.x;          // 256 blocks
    const int b   = bid >> 4;            // batch
    const int jb2 = bid & 15;            // 64-position super-tile
    const int t = threadIdx.x;
    const int w = t >> 6;                // 8 waves
    const int lane = t & 63;
    const int mt   = w >> 2;             // M-tile (16 rows)
    const int half = (w >> 1) & 1;       // channel half (128)
    const int dup  = w & 1;              // ks-half (2 of 4 k-slices)
    const int lrow = lane & 15;
    const int g    = lane >> 4;

    __shared__ float4 xs4[32][65];             // x tile fp32 (reused tile1)
    __shared__ unsigned short cwbf[32][264];   // cw bf16 (block-lifetime)
    __shared__ float  ccred[16][32];
    __shared__ float4 dred[2][2][2][2][64];    // [mt][half][dup][nt][lane]
    __shared__ float  xxr[2][2][2][16];        // [mt][half][dup][pos]
    __shared__ unsigned short xbf[32][264];    // x bf16 (per tile)
    __shared__ unsigned short wT[32][40];      // w^T bf16 (per tile)
    __shared__ float  w_lds[2][32][33];        // fp32 w per tile (wsum)
    __shared__ float  cc_lds[32];
    __shared__ float  sf_lds[32];

    const float4* gx4 = (const float4*)(x + (size_t)b * 1024 * 256)
                        + (size_t)jb2 * 64 * 64;

    // ---- phase 0: DMA tile0 -> xs4; pack cw->bf16 + cc partials; sf ----
#if HAVE_GLOAD_LDS
    #pragma unroll
    for (int i = 0; i < 4; ++i) {
        const int row = w * 4 + i;
        gload_lds16(gx4 + row * 64 + lane, &xs4[row][0]);
    }
#else
    {
        const int p = t >> 4, q = t & 15;
        #pragma unroll
        for (int j = 0; j < 4; ++j)
            xs4[p][q + 16 * j] = gx4[p * 64 + q + 16 * j];
    }
#endif
    {
        const int k = t >> 4, seg = t & 15;  // 16 channels per thread
        const float4* cw4 = (const float4*)cw;
        float s = 0.f;
        #pragma unroll
        for (int jj = 0; jj < 2; ++jj) {
            float4 u0 = cw4[k * 64 + seg * 4 + 2 * jj];
            float4 u1 = cw4[k * 64 + seg * 4 + 2 * jj + 1];
            s += u0.x * u0.x + u0.y * u0.y + u0.z * u0.z + u0.w * u0.w
               + u1.x * u1.x + u1.y * u1.y + u1.z * u1.z + u1.w * u1.w;
            *(short8*)&cwbf[k][seg * 16 + 8 * jj] = pack8(u0, u1);
        }
        ccred[seg][k] = s;
    }
    if (t < 32) sf_lds[t] = sf[t];
    __syncthreads();

    if (t < 32) {                        // overlaps GEMM1; read post-bar1
        float s = 0.f;
        #pragma unroll
        for (int j = 0; j < 16; ++j) s += ccred[j][t];
        cc_lds[t] = s;
    }

    f32x4 E00 = {0,0,0,0}, E01 = {0,0,0,0}, E10 = {0,0,0,0}, E11 = {0,0,0,0};
    const float* xsf = (const float*)xs4;

    #pragma unroll
    for (int tile = 0; tile < 2; ++tile) {
        // ---- GEMM1: dot = x.cw^T (this wave: 2 of 4 k-slices); write xbf ----
        f32x4 D0 = {0,0,0,0}, D1 = {0,0,0,0};
        float xxp = 0.f;
        #pragma unroll
        for (int k2 = 0; k2 < 2; ++k2) {
            const int ks = dup * 2 + k2;
            const int ch = half * 128 + ks * 32 + g * 8;
            const int row = mt * 16 + lrow;
            const float* ap = xsf + row * 260 + ch;
            float4 uu = *(const float4*)ap;
            float4 vv = *(const float4*)(ap + 4);
            xxp += uu.x * uu.x + uu.y * uu.y + uu.z * uu.z + uu.w * uu.w
                 + vv.x * vv.x + vv.y * vv.y + vv.z * vv.z + vv.w * vv.w;
            short8 a = pack8(uu, vv);
            *(short8*)&xbf[row][ch] = a;
            short8 b0 = *(const short8*)&cwbf[lrow][ch];
            short8 b1 = *(const short8*)&cwbf[16 + lrow][ch];
            D0 = __builtin_amdgcn_mfma_f32_16x16x32_bf16(a, b0, D0, 0, 0, 0);
            D1 = __builtin_amdgcn_mfma_f32_16x16x32_bf16(a, b1, D1, 0, 0, 0);
        }
        xxp += __shfl_xor(xxp, 16, 64);
        xxp += __shfl_xor(xxp, 32, 64);
        if (lane < 16) xxr[mt][half][dup][lane] = xxp;
        dred[mt][half][dup][0][lane] = make_float4(D0[0], D0[1], D0[2], D0[3]);
        dred[mt][half][dup][1][lane] = make_float4(D1[0], D1[1], D1[2], D1[3]);
        __syncthreads();                               // bar1

        if (tile == 0) {
            // prefetch tile1 into xs4; stays in flight across raw bar2
#if HAVE_GLOAD_LDS
            #pragma unroll
            for (int i = 0; i < 4; ++i) {
                const int row = w * 4 + i;
                gload_lds16(gx4 + (32 + row) * 64 + lane, &xs4[row][0]);
            }
#else
            const int p = t >> 4, q = t & 15;
            #pragma unroll
            for (int j = 0; j < 4; ++j)
                xs4[p][q + 16 * j] = gx4[(32 + p) * 64 + q + 16 * j];
#endif
        }

        // ---- softmax over k (all waves compute; (half,dup)==(0,0) writes) ---
        {
            const int k0 = lrow, k1 = 16 + lrow;
            float d0[4], d1[4];
            #pragma unroll
            for (int nt = 0; nt < 2; ++nt) {
                float4 s00 = dred[mt][0][0][nt][lane];
                float4 s01 = dred[mt][0][1][nt][lane];
                float4 s10 = dred[mt][1][0][nt][lane];
                float4 s11 = dred[mt][1][1][nt][lane];
                float* dd = nt ? d1 : d0;
                dd[0] = s00.x + s01.x + s10.x + s11.x;
                dd[1] = s00.y + s01.y + s10.y + s11.y;
                dd[2] = s00.z + s01.z + s10.z + s11.z;
                dd[3] = s00.w + s01.w + s10.w + s11.w;
            }
            const float sf0 = sf_lds[k0], sf1 = sf_lds[k1];
            const float cc0 = cc_lds[k0], cc1 = cc_lds[k1];
            #pragma unroll
            for (int r = 0; r < 4; ++r) {
                const int pl = g * 4 + r;
                const float xxv = xxr[mt][0][0][pl] + xxr[mt][0][1][pl]
                                + xxr[mt][1][0][pl] + xxr[mt][1][1][pl];
                float s0 = sf0 * (xxv - 2.f * d0[r] + cc0);
                float s1 = sf1 * (xxv - 2.f * d1[r] + cc1);
                float m = fmaxf(s0, s1);
                #pragma unroll
                for (int msk = 1; msk <= 8; msk <<= 1) m = fmaxf(m, __shfl_xor(m, msk, 64));
                float e0 = __expf(s0 - m), e1 = __expf(s1 - m);
                float sm = e0 + e1;
                #pragma unroll
                for (int msk = 1; msk <= 8; msk <<= 1) sm += __shfl_xor(sm, msk, 64);
                const float inv = 1.f / sm;
                if (half == 0 && dup == 0) {
                    const int n = mt * 16 + pl;
                    const float w0v = e0 * inv, w1v = e1 * inv;
                    w_lds[tile][n][k0] = w0v;
                    w_lds[tile][n][k1] = w1v;
                    wT[k0][n] = f2bf(w0v);
                    wT[k1][n] = f2bf(w1v);
                }
            }
        }
        // bar2: execution + LDS drain only; DMA (vmcnt) stays in flight
        asm volatile("s_waitcnt lgkmcnt(0)" ::: "memory");
        __builtin_amdgcn_sched_barrier(0);
        __builtin_amdgcn_s_barrier();
        __builtin_amdgcn_sched_barrier(0);

        // ---- GEMM2: accumulate S1 fragments across tiles ----
        {
            short8 a0 = *(const short8*)&wT[lrow][8 * g];
            short8 a1 = *(const short8*)&wT[16 + lrow][8 * g];
            const unsigned short* xbu = &xbf[0][0];
            #pragma unroll
            for (int nt = 0; nt < 2; ++nt) {
                const int c = w * 32 + nt * 16 + lrow;
                short8 bf;
                #pragma unroll
                for (int e = 0; e < 8; ++e)
                    bf[e] = (short)xbu[(8 * g + e) * 264 + c];
                if (nt == 0) {
                    E00 = __builtin_amdgcn_mfma_f32_16x16x32_bf16(a0, bf, E00, 0, 0, 0);
                    E10 = __builtin_amdgcn_mfma_f32_16x16x32_bf16(a1, bf, E10, 0, 0, 0);
                } else {
                    E01 = __builtin_amdgcn_mfma_f32_16x16x32_bf16(a0, bf, E01, 0, 0, 0);
                    E11 = __builtin_amdgcn_mfma_f32_16x16x32_bf16(a1, bf, E11, 0, 0, 0);
                }
            }
        }
        if (tile == 0) __syncthreads();    // bar3: drains DMA; xbf/wT reusable
    }

    // ---- stores: one 32x256 partial per block ----
    float* dst = pS1 + (size_t)bid * 8192;
    #pragma unroll
    for (int reg = 0; reg < 4; ++reg) {
        const int k0r = (4 * g + reg) * 256;
        const int k1r = (16 + 4 * g + reg) * 256;
        dst[k0r + w * 32 +  0 + lrow] = E00[reg];
        dst[k0r + w * 32 + 16 + lrow] = E01[reg];
        dst[k1r + w * 32 +  0 + lrow] = E10[reg];
        dst[k1r + w * 32 + 16 + lrow] = E11[reg];
    }
    if (t < 32) {
        float s = 0.f;
        #pragma unroll
        for (int p = 0; p < 32; ++p) s += w_lds[0][p][t] + w_lds[1][p][t];
        pW[bid * 32 + t] = s;
    }
}

// -------- fused reduce + stats (64 blocks x 512 thr, 8 rows/block) -----------
// block bid: batch b = bid>>2, k-group kg = bid&3 -> rows b*32 + kg*8 + [0,8).
// part = t>>8 handles 4 contiguous rows; per-channel partials LDS-combined so
// pst matches R6's stats2 output exactly (enc_out unchanged).
__global__ __launch_bounds__(512) void enc_reduce_stats(
    const float* __restrict__ pS1, const float* __restrict__ pW,
    const float* __restrict__ cw, float* __restrict__ enc,
    float* __restrict__ pst)
{
    __shared__ float sred[2][256];
    __shared__ float ssred[2][256];
    const int bid = blockIdx.x;
    const int b  = bid >> 2;
    const int kg = bid & 3;
    const int t = threadIdx.x;
    const int part = t >> 8;
    const int c = t & 255;

    float s1a = 0.f, s2a = 0.f;
    #pragma unroll
    for (int r8 = 0; r8 < 4; ++r8) {
        const int k = kg * 8 + part * 4 + r8;
        float s = 0.f;
        #pragma unroll
        for (int jj = 0; jj < 16; ++jj)
            s += pS1[(size_t)(b * 16 + jj) * 8192 + k * 256 + c];
        float ws = 0.f;
        #pragma unroll
        for (int jj = 0; jj < 16; ++jj)
            ws += pW[(b * 16 + jj) * 32 + k];   // wave-broadcast loads
        const float e = s - ws * cw[k * 256 + c];
        enc[(b * 32 + k) * 256 + c] = e;
        s1a += e;
        s2a = fmaf(e, e, s2a);
    }
    sred[part][c] = s1a;
    ssred[part][c] = s2a;
    __syncthreads();
    if (t < 256) {
        pst[bid * 512 + c] = sred[0][c] + sred[1][c];
        pst[bid * 512 + 256 + c] = ssred[0][c] + ssred[1][c];
    }
}

// -------- BN finalize + ReLU + sum over k (16 blocks) ------------------------
__global__ __launch_bounds__(256) void enc_out(
    const float* __restrict__ enc, const float* __restrict__ pst,
    const float* __restrict__ gamma, const float* __restrict__ beta,
    float* __restrict__ out)
{
    const int b = blockIdx.x;
    const int c = threadIdx.x;
    float S = 0.f, SS = 0.f;
    #pragma unroll 8
    for (int p = 0; p < 64; ++p) {
        S  += pst[p * 512 + c];
        SS += pst[p * 512 + 256 + c];
    }
    const float mean = S * (1.f / 512.f);
    const float var = SS * (1.f / 512.f) - mean * mean;
    const float g = gamma[c] * rsqrtf(var + BN_EPS);
    const float bt = beta[c];
    float o = 0.f;
    #pragma unroll
    for (int k = 0; k < 32; ++k) {
        float e = enc[(b * 32 + k) * 256 + c];
        float v = (e - mean) * g + bt;
        o += fmaxf(v, 0.f);
    }
    out[b * 256 + c] = o;
}

extern "C" void kernel_launch(void* const* d_in, const int* in_sizes, int n_in,
                              void* d_out, int out_size, void* d_ws, size_t ws_size,
                              hipStream_t stream) {
    const float* x     = (const float*)d_in[0];
    const float* cw    = (const float*)d_in[1];
    const float* sf    = (const float*)d_in[2];
    const float* gamma = (const float*)d_in[3];
    const float* beta  = (const float*)d_in[4];
    float* out = (float*)d_out;
    float* ws  = (float*)d_ws;

    float* pS1 = ws;                               // 256*8192
    float* pW  = pS1 + (size_t)256 * 8192;         // 256*32
    float* enc = pW + (size_t)256 * 32;            // 512*256
    float* pst = enc + (size_t)512 * 256;          // 64*512

    enc_main_mfma<<<256, 512, 0, stream>>>(x, cw, sf, pS1, pW);
    enc_reduce_stats<<<64, 512, 0, stream>>>(pS1, pW, cw, enc, pst);
    enc_out<<<16, 256, 0, stream>>>(enc, pst, gamma, beta, out);
}